// Round 8
// baseline (234.089 us; speedup 1.0000x reference)
//
#include <hip/hip_runtime.h>
#include <math.h>
#include <float.h>

// VideoQuantizer: rmsnorm -> per-subvector argmin over 4096 codewords -> gather -> rmsnorm
// B=8 T=1024 D=1024 Q=8 K=4096 d=128
// v9: barrier-free k_dist. 32-codeword chunks (NCHUNK=128; panel byte layout unchanged),
//     per-wave-private 2x4KB LDS staging ring, counted s_waitcnt vmcnt(5) on the wave's
//     OWN loads only — zero s_barrier in the main loop; waves free-run, 4 blk/CU.
//     tag = chunk (exact 7 bits), k = tag*32 + e. Top-3 insert via min/med3.
//     Tail routing, rescue, out unchanged from v8 (single-pass fp16, TAU=0.04).
#define Q_     8
#define K_     4096
#define dd_    128
#define D_     1024
#define ROWS   8192
#define NCHUNK 128
#define TAU    0.04f   // rescue band on d2/2 scale; fp16 A+B quant (~6+ sigma)

typedef __attribute__((ext_vector_type(8))) _Float16 f16x8;
typedef __attribute__((ext_vector_type(4))) float f32x4;
typedef __attribute__((ext_vector_type(4))) unsigned int u32x4;

typedef const __attribute__((address_space(1))) unsigned int* gas_p;
typedef __attribute__((address_space(3))) unsigned int* las_p;

__device__ inline unsigned f2u(float x) { union { float f; unsigned u; } v; v.f = x; return v.u; }
__device__ inline float u2f(unsigned x) { union { unsigned u; float f; } v; v.u = x; return v.f; }
__device__ inline unsigned short f2h(float x) {
    union { _Float16 h; unsigned short u; } v; v.h = (_Float16)x; return v.u;
}
__device__ inline unsigned umin_(unsigned a, unsigned b) { return a < b ? a : b; }
__device__ inline unsigned umax_(unsigned a, unsigned b) { return a > b ? a : b; }
// order-preserving f32 -> u32 (total order; smaller float -> smaller uint)
__device__ inline unsigned fflip(float x) {
    unsigned u = f2u(x);
    return (u & 0x80000000u) ? ~u : (u | 0x80000000u);
}
__device__ inline unsigned long long shfl_xor_u64(unsigned long long v, int m) {
    unsigned lo = (unsigned)v, hi = (unsigned)(v >> 32);
    lo = __shfl_xor(lo, m, 64);
    hi = __shfl_xor(hi, m, 64);
    return ((unsigned long long)hi << 32) | lo;
}
// decode packed (score|tag) at merge-entry e -> codeword index; tag = chunk (7 bits)
__device__ inline unsigned dec_k(unsigned v, int e) {
    return (v & 0x7Fu) * 32u + (unsigned)e;
}

// ---------------- fused: panel build (negated fp16 plane) + c2/2 | input rmsnorm + x2/2 ----
// panels: row-major rows of 256B, slot = j ^ (row&15) — byte layout chunk-size-agnostic
__global__ void k_prep(const float* __restrict__ cb, const float* __restrict__ x,
                       const float* __restrict__ w, float* __restrict__ xn,
                       unsigned short* __restrict__ panels, float* __restrict__ c2h,
                       float* __restrict__ x2h, int* __restrict__ cntF, int* __restrict__ cntS) {
    const int bid = blockIdx.x, t = threadIdx.x;
    if (bid == 0 && t == 0) { *cntF = 0; *cntS = 0; }
    if (bid < 64 * Q_) {
        // ---- panel prep (64-row tiles; layout identical regardless of k_dist chunking) ----
        int c = bid & 63, q = bid >> 6;
        const float* src = cb + ((size_t)q * K_ + c * 64) * dd_;
        unsigned short* dst = panels + ((size_t)q * 64 + c) * 8192;
        #pragma unroll
        for (int i = 0; i < 4; i++) {
            int sid = i * 256 + t;
            int n = sid >> 4, j = sid & 15;
            const float* sp = src + n * dd_ + j * 8;
            f32x4 v0 = *(const f32x4*)sp;
            f32x4 v1 = *(const f32x4*)(sp + 4);
            float xs[8] = {v0.x, v0.y, v0.z, v0.w, v1.x, v1.y, v1.z, v1.w};
            unsigned short hb[8];
            float ss = 0.0f;
            #pragma unroll
            for (int e = 0; e < 8; e++) {
                float xv = -xs[e];                     // NEGATED codeword
                ss = fmaf(xv, xv, ss);
                hb[e] = f2h(xv);                       // single RTN fp16 plane
            }
            int slot = j ^ (n & 15);
            u32x4 H;
            H.x = (unsigned)hb[0] | ((unsigned)hb[1] << 16);
            H.y = (unsigned)hb[2] | ((unsigned)hb[3] << 16);
            H.z = (unsigned)hb[4] | ((unsigned)hb[5] << 16);
            H.w = (unsigned)hb[6] | ((unsigned)hb[7] << 16);
            *(u32x4*)&dst[(n * 16 + slot) * 8] = H;
            ss += __shfl_xor(ss, 1, 64);
            ss += __shfl_xor(ss, 2, 64);
            ss += __shfl_xor(ss, 4, 64);
            ss += __shfl_xor(ss, 8, 64);
            if (j == 0) c2h[q * K_ + c * 64 + n] = 0.5f * ss;   // exact f32 c2/2
        }
    } else {
        // ---- input rmsnorm + sub-vector x2/2 ----
        int row = bid - 64 * Q_;
        const float4 v = *(const float4*)(x + (size_t)row * D_ + t * 4);
        float ss = v.x * v.x + v.y * v.y + v.z * v.z + v.w * v.w;
        #pragma unroll
        for (int o = 32; o > 0; o >>= 1) ss += __shfl_xor(ss, o, 64);
        __shared__ float acc[4];
        if ((t & 63) == 0) acc[t >> 6] = ss;
        __syncthreads();
        float tot = (acc[0] + acc[1]) + (acc[2] + acc[3]);
        float sc  = 1.0f / sqrtf(tot * (1.0f / D_) + 1e-5f);
        const float4 wv = *(const float4*)(w + t * 4);
        float4 o;
        o.x = v.x * sc * wv.x; o.y = v.y * sc * wv.y;
        o.z = v.z * sc * wv.z; o.w = v.w * sc * wv.w;
        *(float4*)(xn + (size_t)row * D_ + t * 4) = o;
        float so = o.x * o.x + o.y * o.y + o.z * o.z + o.w * o.w;
        so += __shfl_xor(so, 1, 64);
        so += __shfl_xor(so, 2, 64);
        so += __shfl_xor(so, 4, 64);
        so += __shfl_xor(so, 8, 64);
        so += __shfl_xor(so, 16, 64);
        if ((t & 31) == 0) x2h[row * Q_ + (t >> 5)] = 0.5f * so;
    }
}

// one chunk iteration: prefetch C+1 into NXT ring slot + counted wait, compute C, pack
#define ITER(C, CHCUR, CHNXT) do {                                                       \
    if ((C) + 1 < NCHUNK) {                                                              \
        const char* s_ = (const char*)(panels + panq + (size_t)((C) + 1) * 4096)         \
                         + wn * 4096;                                                    \
        char* d_ = mybuf + (((C) + 1) & 1) * 4096;                                       \
        _Pragma("unroll")                                                                \
        for (int i_ = 0; i_ < 4; i_++) {                                                 \
            int o_ = i_ * 1024 + lane * 16;                                              \
            __builtin_amdgcn_global_load_lds((gas_p)(s_ + o_), (las_p)(d_ + o_),         \
                                             16, 0, 0);                                  \
        }                                                                                \
        CHNXT = c2hq[((C) + 1) * 32 + wn * 16 + col];                                    \
        asm volatile("s_waitcnt vmcnt(5)" ::: "memory");                                 \
    } else {                                                                             \
        asm volatile("s_waitcnt vmcnt(0)" ::: "memory");                                 \
    }                                                                                    \
    const char* cb_ = mybuf + ((C) & 1) * 4096;                                          \
    f32x4 acc0 = x2v0 + (CHCUR);                                                         \
    f32x4 acc1 = x2v1 + (CHCUR);                                                         \
    _Pragma("unroll")                                                                    \
    for (int kt_ = 0; kt_ < 4; kt_++) {                                                  \
        f16x8 b_ = *(const f16x8*)(cb_ + col * 256 + (((quad + kt_ * 4) ^ col) * 16));   \
        acc0 = __builtin_amdgcn_mfma_f32_16x16x32_f16(ah[0][kt_], b_, acc0, 0, 0, 0);    \
        acc1 = __builtin_amdgcn_mfma_f32_16x16x32_f16(ah[1][kt_], b_, acc1, 0, 0, 0);    \
    }                                                                                    \
    const unsigned tg_ = (unsigned)(C);                                                  \
    _Pragma("unroll")                                                                    \
    for (int r_ = 0; r_ < 4; r_++) {                                                     \
        unsigned p0_ = (f2u(acc0[r_]) & 0xFFFFFF80u) | tg_;                              \
        unsigned n3_ = umin_(m3[r_], umax_(m2[r_], p0_));                                \
        unsigned n2_ = umax_(m1[r_], umin_(m2[r_], p0_));                                \
        m1[r_] = umin_(m1[r_], p0_); m2[r_] = n2_; m3[r_] = n3_;                         \
        unsigned p1_ = (f2u(acc1[r_]) & 0xFFFFFF80u) | tg_;                              \
        unsigned n3b_ = umin_(m3[4 + r_], umax_(m2[4 + r_], p1_));                       \
        unsigned n2b_ = umax_(m1[4 + r_], umin_(m2[4 + r_], p1_));                       \
        m1[4 + r_] = umin_(m1[4 + r_], p1_); m2[4 + r_] = n2b_; m3[4 + r_] = n3b_;       \
    }                                                                                    \
} while (0)

// ---------------- single-pass fp16 MFMA distance, barrier-free per-wave staging ----------
// x,B both RTN fp16 (negated B). acc init = x2/2 + c2/2 -> acc_final ~ d2/2; pack
// (score&~0x7F)|chunk, u32 top-3 per row-slot. Tail: shortlist from rm1+rm2, full-scan
// fallback when a lane's 3rd (rm3) in band or >5 rivals.
__launch_bounds__(256, 4)
__global__ void k_dist(const float* __restrict__ xn, const unsigned short* __restrict__ panels,
                       const float* __restrict__ c2h, const float* __restrict__ x2h,
                       int* __restrict__ idxi, float* __restrict__ idxf,
                       int* __restrict__ listF, int* __restrict__ cntF,
                       int* __restrict__ srl, int* __restrict__ cntS,
                       unsigned long long* __restrict__ resc,
                       unsigned char* __restrict__ fbm) {
    __shared__ char smem[32768];   // [wave][2][4KB] private rings; merge scratch overlaid

    const int t    = threadIdx.x;
    const int lane = t & 63, wave = t >> 6;
    const int wm = wave >> 1, wn = wave & 1;
    const int col = lane & 15, quad = lane >> 4;
    const int q = blockIdx.y;
    const int row0 = blockIdx.x * 64;

    char* mybuf = smem + wave * 8192;

    // A fragments: single RTN fp16, 2 mt per wave (rows wm*32 + mt*16)
    f16x8 ah[2][4];
    #pragma unroll
    for (int mt = 0; mt < 2; mt++) {
        #pragma unroll
        for (int kt = 0; kt < 4; kt++) {
            const float* ap = xn + (size_t)(row0 + wm * 32 + mt * 16 + col) * D_
                              + q * dd_ + kt * 32 + quad * 8;
            f32x4 v0 = *(const f32x4*)ap;
            f32x4 v1 = *(const f32x4*)(ap + 4);
            #pragma unroll
            for (int e = 0; e < 8; e++) {
                float xv = (e < 4) ? v0[e] : v1[e - 4];
                ah[mt][kt][e] = (_Float16)xv;
            }
        }
    }

    // per-slot row halves of ||x_q||^2
    f32x4 x2v0, x2v1;
    #pragma unroll
    for (int r = 0; r < 4; r++) {
        x2v0[r] = x2h[(size_t)(row0 + wm * 32 + quad * 4 + r) * Q_ + q];
        x2v1[r] = x2h[(size_t)(row0 + wm * 32 + 16 + quad * 4 + r) * Q_ + q];
    }

    unsigned m1[8], m2[8], m3[8];
    #pragma unroll
    for (int i = 0; i < 8; i++) { m1[i] = 0xFFFFFFFFu; m2[i] = 0xFFFFFFFFu; m3[i] = 0xFFFFFFFFu; }

    const size_t panq = (size_t)q * (NCHUNK * 4096);
    const float* c2hq = c2h + q * K_;

    // prologue: stage chunk 0 (private slice) + c2(0)
    float chA, chB;
    {
        const char* s0 = (const char*)(panels + panq) + wn * 4096;
        #pragma unroll
        for (int i = 0; i < 4; i++) {
            int o = i * 1024 + lane * 16;
            __builtin_amdgcn_global_load_lds((gas_p)(s0 + o), (las_p)(mybuf + o), 16, 0, 0);
        }
        chA = c2hq[wn * 16 + col];
    }

    for (int c = 0; c < NCHUNK; c += 2) {
        ITER(c,     chA, chB);
        ITER(c + 1, chB, chA);
    }

    // cross-lane merge per row (u32 domain; stride 33): min + shortlist + fallback detect
    __syncthreads();                              // all waves done -> safe to overlay scratch
    unsigned* rm1 = (unsigned*)smem;              // [64][33]
    unsigned* rm2 = (unsigned*)(smem + 8448);
    unsigned* rm3 = (unsigned*)(smem + 16896);
    #pragma unroll
    for (int mt = 0; mt < 2; mt++) {
        #pragma unroll
        for (int r = 0; r < 4; r++) {
            int sl = mt * 4 + r;
            int row_l = wm * 32 + mt * 16 + quad * 4 + r;
            int e = wn * 16 + col;
            rm1[row_l * 33 + e] = m1[sl];
            rm2[row_l * 33 + e] = m2[sl];
            rm3[row_l * 33 + e] = m3[sl];
        }
    }
    __syncthreads();
    if (t < 64) {
        unsigned b1 = 0xFFFFFFFFu;
        int be = 0;
        for (int e = 0; e < 32; e++) {
            unsigned v1 = rm1[t * 33 + e];
            if (v1 < b1) { b1 = v1; be = e; }
        }
        float thr = u2f(b1 & 0xFFFFFF80u) + TAU;
        int ns = 0, fb = 0;
        unsigned long long candpack = 0;
        for (int e = 0; e < 32; e++) {
            unsigned v1 = rm1[t * 33 + e];
            unsigned v2 = rm2[t * 33 + e];
            unsigned v3 = rm3[t * 33 + e];
            if (u2f(v3 & 0xFFFFFF80u) < thr) fb = 1;   // hidden 4th-in-lane possible
            if (e != be && u2f(v1 & 0xFFFFFF80u) < thr) {
                if (ns < 5) candpack |= (unsigned long long)dec_k(v1, e) << (12 * ns);
                ns++;
            }
            if (u2f(v2 & 0xFFFFFF80u) < thr) {         // lane's 2nd (incl. winner's lane)
                if (ns < 5) candpack |= (unsigned long long)dec_k(v2, e) << (12 * ns);
                ns++;
            }
        }
        if (ns > 5) fb = 1;
        unsigned k1 = dec_k(b1, be);
        int item = (row0 + t) * Q_ + q;
        idxi[item] = (int)k1;
        idxf[item] = (float)k1;
        fbm[item] = (unsigned char)fb;
        if (fb) {
            resc[item] = 0xFFFFFFFFFFFFFFFFull;
            int p = atomicAdd(cntF, 1);
            listF[p] = item;
        } else if (ns > 0) {
            int p = atomicAdd(cntS, 1);
            int* e8 = srl + (size_t)p * 8;
            e8[0] = item; e8[1] = ns + 1; e8[2] = (int)k1;
            for (int i = 0; i < ns; i++)
                e8[3 + i] = (int)((candpack >> (12 * i)) & 0xFFFu);
        }
    }
}

// ---------------- exact fp32 rescue: shortlist blocks (<=6 cand) + full-scan fallback ----
__global__ void k_rescue(const float* __restrict__ xn, const float* __restrict__ cb,
                         const float* __restrict__ c2h, const int* __restrict__ listF,
                         const int* __restrict__ cntF, const int* __restrict__ srl,
                         const int* __restrict__ cntS,
                         unsigned long long* __restrict__ resc,
                         int* __restrict__ idxi, float* __restrict__ idxf) {
    __shared__ float xq[dd_];
    __shared__ unsigned long long kshare[8];
    const int t = threadIdx.x;
    if (blockIdx.x < 2048) {
        // ---- full-scan fallback: 8 blocks/item x 512 codewords ----
        const int n = *cntF;
        const int seg = blockIdx.x & 7;
        for (int ii = blockIdx.x >> 3; ii < n; ii += 256) {
            __syncthreads();
            int item = listF[ii];
            int rg = item >> 3, q = item & 7;
            if (t < dd_) xq[t] = xn[(size_t)rg * D_ + q * dd_ + t];
            __syncthreads();
            unsigned long long best = 0xFFFFFFFFFFFFFFFFull;
            #pragma unroll
            for (int i = 0; i < 2; i++) {
                int k = seg * 512 + i * 256 + t;
                const float* cp = cb + ((size_t)q * K_ + k) * dd_;
                float dot = 0.0f;
                #pragma unroll 8
                for (int d = 0; d < dd_; d += 4) {
                    f32x4 cv = *(const f32x4*)(cp + d);
                    dot = fmaf(cv.x, xq[d],     dot);
                    dot = fmaf(cv.y, xq[d + 1], dot);
                    dot = fmaf(cv.z, xq[d + 2], dot);
                    dot = fmaf(cv.w, xq[d + 3], dot);
                }
                float s = c2h[q * K_ + k] - dot;   // d2/2 - x2/2 (monotone in d2)
                unsigned long long key = ((unsigned long long)fflip(s) << 32) | (unsigned)k;
                best = best < key ? best : key;
            }
            #pragma unroll
            for (int o = 32; o > 0; o >>= 1) {
                unsigned long long other = shfl_xor_u64(best, o);
                best = best < other ? best : other;
            }
            if ((t & 63) == 0) kshare[t >> 6] = best;
            __syncthreads();
            if (t == 0) {
                unsigned long long b = kshare[0];
                b = b < kshare[1] ? b : kshare[1];
                b = b < kshare[2] ? b : kshare[2];
                b = b < kshare[3] ? b : kshare[3];
                atomicMin(&resc[item], b);
            }
        }
    } else {
        // ---- shortlist: 1 block/item, candidate per 32-lane group ----
        const int n = *cntS;
        for (int ii = (int)blockIdx.x - 2048; ii < n; ii += 2048) {
            __syncthreads();
            const int* e = srl + (size_t)ii * 8;
            int item = e[0], nc = e[1];
            int rg = item >> 3, q = item & 7;
            if (t < dd_) xq[t] = xn[(size_t)rg * D_ + q * dd_ + t];
            __syncthreads();
            int g = t >> 5, l = t & 31;
            unsigned long long key = 0xFFFFFFFFFFFFFFFFull;
            if (g < nc) {
                int k = e[2 + g];
                const float* cp = cb + ((size_t)q * K_ + k) * dd_ + l * 4;
                f32x4 cv = *(const f32x4*)cp;
                float dot = cv.x * xq[l * 4]     + cv.y * xq[l * 4 + 1]
                          + cv.z * xq[l * 4 + 2] + cv.w * xq[l * 4 + 3];
                dot += __shfl_xor(dot, 16, 64);
                dot += __shfl_xor(dot, 8, 64);
                dot += __shfl_xor(dot, 4, 64);
                dot += __shfl_xor(dot, 2, 64);
                dot += __shfl_xor(dot, 1, 64);
                float s = c2h[q * K_ + k] - dot;
                key = ((unsigned long long)fflip(s) << 32) | (unsigned)k;
            }
            if (l == 0) kshare[g] = key;
            __syncthreads();
            if (t == 0) {
                unsigned long long b = kshare[0];
                #pragma unroll
                for (int gg = 1; gg < 8; gg++) b = b < kshare[gg] ? b : kshare[gg];
                int k = (int)(unsigned)(b & 0xFFFFFFFFull);
                idxi[item] = k;
                idxf[item] = (float)k;
            }
        }
    }
}

// ---------------- gather + output rmsnorm (+ fold-in of fallback decode) ----------------
__global__ void k_out(const float* __restrict__ cb, const int* __restrict__ idx_i,
                      const unsigned long long* __restrict__ resc,
                      const unsigned char* __restrict__ fbm,
                      const float* __restrict__ w, float* __restrict__ out,
                      float* __restrict__ idxf) {
    int row = blockIdx.x;
    int t   = threadIdx.x;
    __shared__ int   sidx[Q_];
    __shared__ float acc[4];
    if (t < Q_) {
        int item = row * Q_ + t;
        int k = idx_i[item];
        if (fbm[item]) {                       // fallback winner decoded here (k_fin folded)
            k = (int)(unsigned)(resc[item] & 0xFFFFFFFFull);
            idxf[item] = (float)k;
        }
        sidx[t] = k;
    }
    __syncthreads();
    int col = t * 4;
    int q   = col >> 7;
    int dc  = col & 127;
    const float4 v = *(const float4*)(cb + ((size_t)q * K_ + sidx[q]) * dd_ + dc);
    float ss = v.x * v.x + v.y * v.y + v.z * v.z + v.w * v.w;
    #pragma unroll
    for (int o = 32; o > 0; o >>= 1) ss += __shfl_xor(ss, o, 64);
    if ((t & 63) == 0) acc[t >> 6] = ss;
    __syncthreads();
    float tot = (acc[0] + acc[1]) + (acc[2] + acc[3]);
    float sc  = 1.0f / sqrtf(tot * (1.0f / D_) + 1e-5f);
    const float4 wv = *(const float4*)(w + col);
    float4 o;
    o.x = v.x * sc * wv.x; o.y = v.y * sc * wv.y;
    o.z = v.z * sc * wv.z; o.w = v.w * sc * wv.w;
    *(float4*)(out + (size_t)row * D_ + col) = o;
}

extern "C" void kernel_launch(void* const* d_in, const int* in_sizes, int n_in,
                              void* d_out, int out_size, void* d_ws, size_t ws_size,
                              hipStream_t stream) {
    const float* x     = (const float*)d_in[0];
    const float* cb    = (const float*)d_in[1];
    const float* w_in  = (const float*)d_in[2];
    const float* w_out = (const float*)d_in[3];

    float* out  = (float*)d_out;                  // xn lives here between k_prep and k_out
    float* idxf = out + (size_t)ROWS * D_;

    // ws: panels 8MB | c2h 128KB | x2h 256KB | resc 512KB | idxi 256KB | listF 256KB
    //   | srl 2MB | fbm 64KB | cntF,cntS
    unsigned short* panels = (unsigned short*)d_ws;
    float* c2h  = (float*)((char*)d_ws + (8u << 20));
    float* x2h  = c2h + Q_ * K_;
    unsigned long long* resc = (unsigned long long*)(x2h + (size_t)ROWS * Q_);
    int*   idxi = (int*)(resc + (size_t)ROWS * Q_);
    int*   listF = idxi + ROWS * Q_;
    int*   srl  = listF + ROWS * Q_;
    unsigned char* fbm = (unsigned char*)(srl + (size_t)ROWS * Q_ * 8);
    int*   cntF = (int*)(fbm + ROWS * Q_);
    int*   cntS = cntF + 1;

    k_prep  <<<dim3(64 * Q_ + ROWS), 256, 0, stream>>>(cb, x, w_in, out, panels, c2h, x2h, cntF, cntS);
    k_dist  <<<dim3(ROWS / 64, Q_),  256, 0, stream>>>(out, panels, c2h, x2h, idxi, idxf, listF, cntF, srl, cntS, resc, fbm);
    k_rescue<<<dim3(4096),           256, 0, stream>>>(out, cb, c2h, listF, cntF, srl, cntS, resc, idxi, idxf);
    k_out   <<<dim3(ROWS),           256, 0, stream>>>(cb, idxi, resc, fbm, w_out, out, idxf);
}

// Round 9
// 213.547 us; speedup vs baseline: 1.0962x; 1.0962x over previous
//
#include <hip/hip_runtime.h>
#include <math.h>
#include <float.h>

// VideoQuantizer: rmsnorm -> per-subvector argmin over 4096 codewords -> gather -> rmsnorm
// B=8 T=1024 D=1024 Q=8 K=4096 d=128
// v10: revert to v8 structure (best k_dist: 120us; v9 barrier-free duplicated staging and
//      regressed). Change: top-3 pack via v_med3_u32 sequential insert — 8 ops/pair vs 11
//      (bit-identical top-3 multiset). Everything else identical to v8.
#define Q_     8
#define K_     4096
#define dd_    128
#define D_     1024
#define ROWS   8192
#define NCHUNK 64
#define TAU    0.04f   // rescue band on d2/2 scale; fp16 A+B quant (~6 sigma)

typedef __attribute__((ext_vector_type(8))) _Float16 f16x8;
typedef __attribute__((ext_vector_type(4))) float f32x4;
typedef __attribute__((ext_vector_type(4))) unsigned int u32x4;

typedef const __attribute__((address_space(1))) unsigned int* gas_p;
typedef __attribute__((address_space(3))) unsigned int* las_p;

__device__ inline unsigned f2u(float x) { union { float f; unsigned u; } v; v.f = x; return v.u; }
__device__ inline float u2f(unsigned x) { union { unsigned u; float f; } v; v.u = x; return v.f; }
__device__ inline unsigned short f2h(float x) {
    union { _Float16 h; unsigned short u; } v; v.h = (_Float16)x; return v.u;
}
__device__ inline unsigned umin_(unsigned a, unsigned b) { return a < b ? a : b; }
__device__ inline unsigned umax_(unsigned a, unsigned b) { return a > b ? a : b; }
// single-instruction integer median-of-3 (V_MED3_U32, gfx9+ VOP3)
__device__ inline unsigned med3u(unsigned a, unsigned b, unsigned c) {
    unsigned d;
    asm("v_med3_u32 %0, %1, %2, %3" : "=v"(d) : "v"(a), "v"(b), "v"(c));
    return d;
}
// order-preserving f32 -> u32 (total order; smaller float -> smaller uint)
__device__ inline unsigned fflip(float x) {
    unsigned u = f2u(x);
    return (u & 0x80000000u) ? ~u : (u | 0x80000000u);
}
__device__ inline unsigned long long shfl_xor_u64(unsigned long long v, int m) {
    unsigned lo = (unsigned)v, hi = (unsigned)(v >> 32);
    lo = __shfl_xor(lo, m, 64);
    hi = __shfl_xor(hi, m, 64);
    return ((unsigned long long)hi << 32) | lo;
}
// decode packed (tag|lane) -> codeword index; tag = (chunk<<1)|halfcol, e = lane index
__device__ inline unsigned dec_k(unsigned v, int e) {
    unsigned tg = v & 0x7Fu;
    return ((tg >> 1) << 6) | (((unsigned)e >> 4) << 5) | ((tg & 1u) << 4) | ((unsigned)e & 15u);
}

// ---------------- fused: panel build (negated fp16 plane) + c2/2 | input rmsnorm + x2/2 ----
// panels[q][c][n][slot][8 fp16] of NEGATED codewords; slot = j ^ (n&15)
__global__ void k_prep(const float* __restrict__ cb, const float* __restrict__ x,
                       const float* __restrict__ w, float* __restrict__ xn,
                       unsigned short* __restrict__ panels, float* __restrict__ c2h,
                       float* __restrict__ x2h, int* __restrict__ cntF, int* __restrict__ cntS) {
    const int bid = blockIdx.x, t = threadIdx.x;
    if (bid == 0 && t == 0) { *cntF = 0; *cntS = 0; }
    if (bid < NCHUNK * Q_) {
        // ---- panel prep ----
        int c = bid & 63, q = bid >> 6;
        const float* src = cb + ((size_t)q * K_ + c * 64) * dd_;
        unsigned short* dst = panels + (size_t)(q * NCHUNK + c) * 8192;
        #pragma unroll
        for (int i = 0; i < 4; i++) {
            int sid = i * 256 + t;
            int n = sid >> 4, j = sid & 15;
            const float* sp = src + n * dd_ + j * 8;
            f32x4 v0 = *(const f32x4*)sp;
            f32x4 v1 = *(const f32x4*)(sp + 4);
            float xs[8] = {v0.x, v0.y, v0.z, v0.w, v1.x, v1.y, v1.z, v1.w};
            unsigned short hb[8];
            float ss = 0.0f;
            #pragma unroll
            for (int e = 0; e < 8; e++) {
                float xv = -xs[e];                     // NEGATED codeword
                ss = fmaf(xv, xv, ss);
                hb[e] = f2h(xv);                       // single RTN fp16 plane
            }
            int slot = j ^ (n & 15);
            u32x4 H;
            H.x = (unsigned)hb[0] | ((unsigned)hb[1] << 16);
            H.y = (unsigned)hb[2] | ((unsigned)hb[3] << 16);
            H.z = (unsigned)hb[4] | ((unsigned)hb[5] << 16);
            H.w = (unsigned)hb[6] | ((unsigned)hb[7] << 16);
            *(u32x4*)&dst[(n * 16 + slot) * 8] = H;
            ss += __shfl_xor(ss, 1, 64);
            ss += __shfl_xor(ss, 2, 64);
            ss += __shfl_xor(ss, 4, 64);
            ss += __shfl_xor(ss, 8, 64);
            if (j == 0) c2h[q * K_ + c * 64 + n] = 0.5f * ss;   // exact f32 c2/2
        }
    } else {
        // ---- input rmsnorm + sub-vector x2/2 ----
        int row = bid - NCHUNK * Q_;
        const float4 v = *(const float4*)(x + (size_t)row * D_ + t * 4);
        float ss = v.x * v.x + v.y * v.y + v.z * v.z + v.w * v.w;
        #pragma unroll
        for (int o = 32; o > 0; o >>= 1) ss += __shfl_xor(ss, o, 64);
        __shared__ float acc[4];
        if ((t & 63) == 0) acc[t >> 6] = ss;
        __syncthreads();
        float tot = (acc[0] + acc[1]) + (acc[2] + acc[3]);
        float sc  = 1.0f / sqrtf(tot * (1.0f / D_) + 1e-5f);
        const float4 wv = *(const float4*)(w + t * 4);
        float4 o;
        o.x = v.x * sc * wv.x; o.y = v.y * sc * wv.y;
        o.z = v.z * sc * wv.z; o.w = v.w * sc * wv.w;
        *(float4*)(xn + (size_t)row * D_ + t * 4) = o;
        float so = o.x * o.x + o.y * o.y + o.z * o.z + o.w * o.w;
        so += __shfl_xor(so, 1, 64);
        so += __shfl_xor(so, 2, 64);
        so += __shfl_xor(so, 4, 64);
        so += __shfl_xor(so, 8, 64);
        so += __shfl_xor(so, 16, 64);
        if ((t & 31) == 0) x2h[row * Q_ + (t >> 5)] = 0.5f * so;
    }
}

// stage chunk CN's 16KB panel into its alternating 16KB LDS buffer
#define STAGE(CN) do {                                                                   \
    const char* src_ = (const char*)(panels + panq + (size_t)(CN) * 8192);               \
    char* stg_ = smem + ((CN) & 1) * 16384;                                              \
    _Pragma("unroll")                                                                    \
    for (int i_ = 0; i_ < 4; i_++) {                                                     \
        int boff_ = i_ * 4096 + t * 16;                                                  \
        __builtin_amdgcn_global_load_lds((gas_p)(src_ + boff_), (las_p)(stg_ + boff_),   \
                                         16, 0, 0);                                      \
    }                                                                                    \
} while (0)

// ---------------- single-pass fp16 MFMA distance (64-row blocks) + med3 top-3 ------------
// x,B both RTN fp16 (negated B). acc init = x2/2 + c2/2 -> acc_final ~ d2/2 (err<=TAU/2);
// pack (score&~0x7F)|tag, v_med3_u32 sequential top-3 insert. Tail routing: shortlist from
// rm1+rm2, full-scan fallback only when a lane's 3rd (rm3) is in band or >5 rivals.
__launch_bounds__(256, 4)
__global__ void k_dist(const float* __restrict__ xn, const unsigned short* __restrict__ panels,
                       const float* __restrict__ c2h, const float* __restrict__ x2h,
                       int* __restrict__ idxi, float* __restrict__ idxf,
                       int* __restrict__ listF, int* __restrict__ cntF,
                       int* __restrict__ srl, int* __restrict__ cntS,
                       unsigned long long* __restrict__ resc,
                       unsigned char* __restrict__ fbm) {
    __shared__ char smem[32768];   // 2 x 16KB staging; reduce scratch (25344B) overlaid

    const int t    = threadIdx.x;
    const int lane = t & 63, wave = t >> 6;
    const int wm = wave >> 1, wn = wave & 1;
    const int col = lane & 15, quad = lane >> 4;
    const int q = blockIdx.y;
    const int row0 = blockIdx.x * 64;

    // A fragments: single RTN fp16, 2 mt per wave
    f16x8 ah[2][4];
    #pragma unroll
    for (int mt = 0; mt < 2; mt++) {
        #pragma unroll
        for (int kt = 0; kt < 4; kt++) {
            const float* ap = xn + (size_t)(row0 + wm * 32 + mt * 16 + col) * D_
                              + q * dd_ + kt * 32 + quad * 8;
            f32x4 v0 = *(const f32x4*)ap;
            f32x4 v1 = *(const f32x4*)(ap + 4);
            #pragma unroll
            for (int e = 0; e < 8; e++) {
                float xv = (e < 4) ? v0[e] : v1[e - 4];
                ah[mt][kt][e] = (_Float16)xv;
            }
        }
    }

    // per-slot row halves of ||x_q||^2
    f32x4 x2v[2];
    #pragma unroll
    for (int mt = 0; mt < 2; mt++)
        #pragma unroll
        for (int r = 0; r < 4; r++)
            x2v[mt][r] = x2h[(size_t)(row0 + wm * 32 + mt * 16 + quad * 4 + r) * Q_ + q];

    unsigned m1[8], m2[8], m3[8];
    #pragma unroll
    for (int i = 0; i < 8; i++) { m1[i] = 0xFFFFFFFFu; m2[i] = 0xFFFFFFFFu; m3[i] = 0xFFFFFFFFu; }

    const size_t panq = (size_t)q * NCHUNK * 8192;
    const float* c2hq = c2h + q * K_;

    STAGE(0);
    float ch0 = c2hq[wn * 32 + col];
    float ch1 = c2hq[wn * 32 + col + 16];

    for (int c = 0; c < NCHUNK; c++) {
        __syncthreads();
        if (c + 1 < NCHUNK) STAGE(c + 1);
        float ch0n = 0.0f, ch1n = 0.0f;
        if (c + 1 < NCHUNK) {
            ch0n = c2hq[(c + 1) * 64 + wn * 32 + col];
            ch1n = c2hq[(c + 1) * 64 + wn * 32 + col + 16];
        }
        const char* cbuf = smem + (c & 1) * 16384;

        f32x4 acc[2][2];
        #pragma unroll
        for (int mt = 0; mt < 2; mt++) {
            acc[mt][0] = x2v[mt] + ch0;   // d2/2 accumulator init
            acc[mt][1] = x2v[mt] + ch1;
        }

        #pragma unroll
        for (int kt = 0; kt < 4; kt++) {
            const int sw = ((quad + kt * 4) ^ col) * 16;
            const int a0 = (wn * 32 + col) * 256 + sw;        // codeword rows 0..15 of half 0
            const int a1 = a0 + 4096;                         // +16 rows (half 1)
            f16x8 b0 = *(const f16x8*)(cbuf + a0);
            f16x8 b1 = *(const f16x8*)(cbuf + a1);
            #pragma unroll
            for (int mt = 0; mt < 2; mt++) {
                acc[mt][0] = __builtin_amdgcn_mfma_f32_16x16x32_f16(ah[mt][kt], b0, acc[mt][0], 0, 0, 0);
                acc[mt][1] = __builtin_amdgcn_mfma_f32_16x16x32_f16(ah[mt][kt], b1, acc[mt][1], 0, 0, 0);
            }
        }

        const unsigned tg0 = (unsigned)(c << 1), tg1 = tg0 | 1u;
        #pragma unroll
        for (int mt = 0; mt < 2; mt++) {
            #pragma unroll
            for (int r = 0; r < 4; r++) {
                const int sl = mt * 4 + r;
                unsigned p0 = (f2u(acc[mt][0][r]) & 0xFFFFFF80u) | tg0;
                m3[sl] = med3u(m2[sl], m3[sl], p0);
                m2[sl] = med3u(m1[sl], m2[sl], p0);
                m1[sl] = umin_(m1[sl], p0);
                unsigned p1 = (f2u(acc[mt][1][r]) & 0xFFFFFF80u) | tg1;
                m3[sl] = med3u(m2[sl], m3[sl], p1);
                m2[sl] = med3u(m1[sl], m2[sl], p1);
                m1[sl] = umin_(m1[sl], p1);
            }
        }
        ch0 = ch0n; ch1 = ch1n;
    }

    // cross-lane merge per row (u32 domain; stride 33): min + shortlist + fallback detect
    __syncthreads();
    unsigned* rm1 = (unsigned*)smem;             // [64][33]
    unsigned* rm2 = (unsigned*)(smem + 8448);
    unsigned* rm3 = (unsigned*)(smem + 16896);
    #pragma unroll
    for (int mt = 0; mt < 2; mt++) {
        #pragma unroll
        for (int r = 0; r < 4; r++) {
            int sl = mt * 4 + r;
            int row_l = wm * 32 + mt * 16 + quad * 4 + r;
            int e = wn * 16 + col;
            rm1[row_l * 33 + e] = m1[sl];
            rm2[row_l * 33 + e] = m2[sl];
            rm3[row_l * 33 + e] = m3[sl];
        }
    }
    __syncthreads();
    if (t < 64) {
        unsigned b1 = 0xFFFFFFFFu;
        int be = 0;
        for (int e = 0; e < 32; e++) {
            unsigned v1 = rm1[t * 33 + e];
            if (v1 < b1) { b1 = v1; be = e; }
        }
        float thr = u2f(b1 & 0xFFFFFF80u) + TAU;
        int ns = 0, fb = 0;
        unsigned long long candpack = 0;
        for (int e = 0; e < 32; e++) {
            unsigned v1 = rm1[t * 33 + e];
            unsigned v2 = rm2[t * 33 + e];
            unsigned v3 = rm3[t * 33 + e];
            if (u2f(v3 & 0xFFFFFF80u) < thr) fb = 1;   // hidden 4th-in-lane possible
            if (e != be && u2f(v1 & 0xFFFFFF80u) < thr) {
                if (ns < 5) candpack |= (unsigned long long)dec_k(v1, e) << (12 * ns);
                ns++;
            }
            if (u2f(v2 & 0xFFFFFF80u) < thr) {         // lane's 2nd (incl. winner's lane)
                if (ns < 5) candpack |= (unsigned long long)dec_k(v2, e) << (12 * ns);
                ns++;
            }
        }
        if (ns > 5) fb = 1;
        unsigned k1 = dec_k(b1, be);
        int item = (row0 + t) * Q_ + q;
        idxi[item] = (int)k1;
        idxf[item] = (float)k1;
        fbm[item] = (unsigned char)fb;
        if (fb) {
            resc[item] = 0xFFFFFFFFFFFFFFFFull;
            int p = atomicAdd(cntF, 1);
            listF[p] = item;
        } else if (ns > 0) {
            int p = atomicAdd(cntS, 1);
            int* e8 = srl + (size_t)p * 8;
            e8[0] = item; e8[1] = ns + 1; e8[2] = (int)k1;
            for (int i = 0; i < ns; i++)
                e8[3 + i] = (int)((candpack >> (12 * i)) & 0xFFFu);
        }
    }
}

// ---------------- exact fp32 rescue: shortlist blocks (<=6 cand) + full-scan fallback ----
__global__ void k_rescue(const float* __restrict__ xn, const float* __restrict__ cb,
                         const float* __restrict__ c2h, const int* __restrict__ listF,
                         const int* __restrict__ cntF, const int* __restrict__ srl,
                         const int* __restrict__ cntS,
                         unsigned long long* __restrict__ resc,
                         int* __restrict__ idxi, float* __restrict__ idxf) {
    __shared__ float xq[dd_];
    __shared__ unsigned long long kshare[8];
    const int t = threadIdx.x;
    if (blockIdx.x < 2048) {
        // ---- full-scan fallback: 8 blocks/item x 512 codewords ----
        const int n = *cntF;
        const int seg = blockIdx.x & 7;
        for (int ii = blockIdx.x >> 3; ii < n; ii += 256) {
            __syncthreads();
            int item = listF[ii];
            int rg = item >> 3, q = item & 7;
            if (t < dd_) xq[t] = xn[(size_t)rg * D_ + q * dd_ + t];
            __syncthreads();
            unsigned long long best = 0xFFFFFFFFFFFFFFFFull;
            #pragma unroll
            for (int i = 0; i < 2; i++) {
                int k = seg * 512 + i * 256 + t;
                const float* cp = cb + ((size_t)q * K_ + k) * dd_;
                float dot = 0.0f;
                #pragma unroll 8
                for (int d = 0; d < dd_; d += 4) {
                    f32x4 cv = *(const f32x4*)(cp + d);
                    dot = fmaf(cv.x, xq[d],     dot);
                    dot = fmaf(cv.y, xq[d + 1], dot);
                    dot = fmaf(cv.z, xq[d + 2], dot);
                    dot = fmaf(cv.w, xq[d + 3], dot);
                }
                float s = c2h[q * K_ + k] - dot;   // d2/2 - x2/2 (monotone in d2)
                unsigned long long key = ((unsigned long long)fflip(s) << 32) | (unsigned)k;
                best = best < key ? best : key;
            }
            #pragma unroll
            for (int o = 32; o > 0; o >>= 1) {
                unsigned long long other = shfl_xor_u64(best, o);
                best = best < other ? best : other;
            }
            if ((t & 63) == 0) kshare[t >> 6] = best;
            __syncthreads();
            if (t == 0) {
                unsigned long long b = kshare[0];
                b = b < kshare[1] ? b : kshare[1];
                b = b < kshare[2] ? b : kshare[2];
                b = b < kshare[3] ? b : kshare[3];
                atomicMin(&resc[item], b);
            }
        }
    } else {
        // ---- shortlist: 1 block/item, candidate per 32-lane group ----
        const int n = *cntS;
        for (int ii = (int)blockIdx.x - 2048; ii < n; ii += 2048) {
            __syncthreads();
            const int* e = srl + (size_t)ii * 8;
            int item = e[0], nc = e[1];
            int rg = item >> 3, q = item & 7;
            if (t < dd_) xq[t] = xn[(size_t)rg * D_ + q * dd_ + t];
            __syncthreads();
            int g = t >> 5, l = t & 31;
            unsigned long long key = 0xFFFFFFFFFFFFFFFFull;
            if (g < nc) {
                int k = e[2 + g];
                const float* cp = cb + ((size_t)q * K_ + k) * dd_ + l * 4;
                f32x4 cv = *(const f32x4*)cp;
                float dot = cv.x * xq[l * 4]     + cv.y * xq[l * 4 + 1]
                          + cv.z * xq[l * 4 + 2] + cv.w * xq[l * 4 + 3];
                dot += __shfl_xor(dot, 16, 64);
                dot += __shfl_xor(dot, 8, 64);
                dot += __shfl_xor(dot, 4, 64);
                dot += __shfl_xor(dot, 2, 64);
                dot += __shfl_xor(dot, 1, 64);
                float s = c2h[q * K_ + k] - dot;
                key = ((unsigned long long)fflip(s) << 32) | (unsigned)k;
            }
            if (l == 0) kshare[g] = key;
            __syncthreads();
            if (t == 0) {
                unsigned long long b = kshare[0];
                #pragma unroll
                for (int gg = 1; gg < 8; gg++) b = b < kshare[gg] ? b : kshare[gg];
                int k = (int)(unsigned)(b & 0xFFFFFFFFull);
                idxi[item] = k;
                idxf[item] = (float)k;
            }
        }
    }
}

// ---------------- gather + output rmsnorm (+ fold-in of fallback decode) ----------------
__global__ void k_out(const float* __restrict__ cb, const int* __restrict__ idx_i,
                      const unsigned long long* __restrict__ resc,
                      const unsigned char* __restrict__ fbm,
                      const float* __restrict__ w, float* __restrict__ out,
                      float* __restrict__ idxf) {
    int row = blockIdx.x;
    int t   = threadIdx.x;
    __shared__ int   sidx[Q_];
    __shared__ float acc[4];
    if (t < Q_) {
        int item = row * Q_ + t;
        int k = idx_i[item];
        if (fbm[item]) {                       // fallback winner decoded here (k_fin folded)
            k = (int)(unsigned)(resc[item] & 0xFFFFFFFFull);
            idxf[item] = (float)k;
        }
        sidx[t] = k;
    }
    __syncthreads();
    int col = t * 4;
    int q   = col >> 7;
    int dc  = col & 127;
    const float4 v = *(const float4*)(cb + ((size_t)q * K_ + sidx[q]) * dd_ + dc);
    float ss = v.x * v.x + v.y * v.y + v.z * v.z + v.w * v.w;
    #pragma unroll
    for (int o = 32; o > 0; o >>= 1) ss += __shfl_xor(ss, o, 64);
    if ((t & 63) == 0) acc[t >> 6] = ss;
    __syncthreads();
    float tot = (acc[0] + acc[1]) + (acc[2] + acc[3]);
    float sc  = 1.0f / sqrtf(tot * (1.0f / D_) + 1e-5f);
    const float4 wv = *(const float4*)(w + col);
    float4 o;
    o.x = v.x * sc * wv.x; o.y = v.y * sc * wv.y;
    o.z = v.z * sc * wv.z; o.w = v.w * sc * wv.w;
    *(float4*)(out + (size_t)row * D_ + col) = o;
}

extern "C" void kernel_launch(void* const* d_in, const int* in_sizes, int n_in,
                              void* d_out, int out_size, void* d_ws, size_t ws_size,
                              hipStream_t stream) {
    const float* x     = (const float*)d_in[0];
    const float* cb    = (const float*)d_in[1];
    const float* w_in  = (const float*)d_in[2];
    const float* w_out = (const float*)d_in[3];

    float* out  = (float*)d_out;                  // xn lives here between k_prep and k_out
    float* idxf = out + (size_t)ROWS * D_;

    // ws: panels 8MB | c2h 128KB | x2h 256KB | resc 512KB | idxi 256KB | listF 256KB
    //   | srl 2MB | fbm 64KB | cntF,cntS
    unsigned short* panels = (unsigned short*)d_ws;
    float* c2h  = (float*)((char*)d_ws + (8u << 20));
    float* x2h  = c2h + Q_ * K_;
    unsigned long long* resc = (unsigned long long*)(x2h + (size_t)ROWS * Q_);
    int*   idxi = (int*)(resc + (size_t)ROWS * Q_);
    int*   listF = idxi + ROWS * Q_;
    int*   srl  = listF + ROWS * Q_;
    unsigned char* fbm = (unsigned char*)(srl + (size_t)ROWS * Q_ * 8);
    int*   cntF = (int*)(fbm + ROWS * Q_);
    int*   cntS = cntF + 1;

    k_prep  <<<dim3(NCHUNK * Q_ + ROWS), 256, 0, stream>>>(cb, x, w_in, out, panels, c2h, x2h, cntF, cntS);
    k_dist  <<<dim3(ROWS / 64, Q_),      256, 0, stream>>>(out, panels, c2h, x2h, idxi, idxf, listF, cntF, srl, cntS, resc, fbm);
    k_rescue<<<dim3(4096),               256, 0, stream>>>(out, cb, c2h, listF, cntF, srl, cntS, resc, idxi, idxf);
    k_out   <<<dim3(ROWS),               256, 0, stream>>>(cb, idxi, resc, fbm, w_out, out, idxf);
}